// Round 1
// baseline (266.722 us; speedup 1.0000x reference)
//
#include <hip/hip_runtime.h>
#include <hip/hip_bf16.h>
#include <math.h>

#define D_SSM 512
#define D_STATE 16
#define CKPT_BASE 511     // first index of level 9
#define CKPT_END 1023     // first index of level 10
#define N_CKPT 512        // nodes at level 9
#define MPAD 16384

typedef __attribute__((ext_vector_type(8))) short short8;
typedef __attribute__((ext_vector_type(4))) float floatx4;

__device__ __forceinline__ unsigned short f2bf(float f) {
    unsigned int u = __float_as_uint(f);
    unsigned int r = (u + 0x7fffu + ((u >> 16) & 1u)) >> 16;
    return (unsigned short)r;
}
__device__ __forceinline__ float bf2f(unsigned short u) {
    return __uint_as_float(((unsigned int)u) << 16);
}
__device__ __forceinline__ void g2lds16(const void* g, void* l) {
    __builtin_amdgcn_global_load_lds(
        (const __attribute__((address_space(1))) void*)g,
        (__attribute__((address_space(3))) void*)l, 16, 0, 0);
}

// ---------------- prep: cast s/W_in/W_delta to bf16; W2 = [W_delta; W_B; W_C; 0] (640 rows) ----------------
__global__ __launch_bounds__(256) void prep_kernel(
    const float* __restrict__ s, const float* __restrict__ w,
    const float* __restrict__ W_in, const float* __restrict__ W_delta,
    const float* __restrict__ W_B, const float* __restrict__ W_C,
    unsigned short* __restrict__ s_bf, float* __restrict__ lw,
    unsigned short* __restrict__ Win_bf, unsigned short* __restrict__ Wd_bf,
    int Nn)
{
    const int b = blockIdx.x, t = threadIdx.x;
    if (b < MPAD) {
        unsigned int pack = 0;
        if (b < Nn) {
            float2 sv = *(const float2*)(s + (size_t)b * 512 + t * 2);
            pack = (unsigned int)f2bf(sv.x) | ((unsigned int)f2bf(sv.y) << 16);
        }
        *(unsigned int*)(s_bf + (size_t)b * 512 + t * 2) = pack;
        if (t == 0) lw[b] = (b < Nn) ? logf(w[b] + 1e-6f) : 0.f;
    } else if (b < MPAD + 512) {
        int c = b - MPAD;
        float a0 = W_in[(size_t)c * 513 + t * 2];
        float a1 = W_in[(size_t)c * 513 + t * 2 + 1];
        *(unsigned int*)(Win_bf + (size_t)c * 512 + t * 2) =
            (unsigned int)f2bf(a0) | ((unsigned int)f2bf(a1) << 16);
    } else if (b < MPAD + 1024) {
        int c = b - MPAD - 512;
        float2 wv = *(const float2*)(W_delta + (size_t)c * 512 + t * 2);
        *(unsigned int*)(Wd_bf + (size_t)c * 512 + t * 2) =
            (unsigned int)f2bf(wv.x) | ((unsigned int)f2bf(wv.y) << 16);
    } else {
        // rows 512..639 of W2: 0..15 = W_B, 16..31 = W_C, rest zero padding
        int c = b - MPAD - 1024;   // 0..127
        float2 wv; wv.x = 0.f; wv.y = 0.f;
        if (c < 16)      wv = *(const float2*)(W_B + (size_t)c * 512 + t * 2);
        else if (c < 32) wv = *(const float2*)(W_C + (size_t)(c - 16) * 512 + t * 2);
        *(unsigned int*)(Wd_bf + (size_t)(512 + c) * 512 + t * 2) =
            (unsigned int)f2bf(wv.x) | ((unsigned int)f2bf(wv.y) << 16);
    }
}

// ---------------- bf16 MFMA GEMM, 64x128 tile, 3-stage LDS ring + counted vmcnt ----------------
// mode 0: o = z + bias[c] + lw[r]*wcol[c*wcol_stride]; store bf16 -> outbf
// mode 1: o = softplus(z+bias[c]) * sigmoid(lw[r]*wcol[c]+bw[c]); store fp32 -> outf
// col tile with col0 >= 512 (mode 1 only): cols 512..543 are B/C -> Bm/Cm
__global__ __launch_bounds__(256) void gemm_mfma(
    const unsigned short* __restrict__ Abf,   // [16384][512] bf16
    const unsigned short* __restrict__ Wbf,   // [512 or 640][512] bf16
    float* __restrict__ outf,
    unsigned short* __restrict__ outbf,
    const float* __restrict__ bias,
    const float* __restrict__ lw,
    const float* __restrict__ wcol, int wcol_stride,
    const float* __restrict__ bw,
    const float* __restrict__ b_B, const float* __restrict__ b_C,
    float* __restrict__ Bm, float* __restrict__ Cm,
    int mode)
{
    __shared__ __align__(16) short As[3][64 * 32];    // 4 KB per stage
    __shared__ __align__(16) short Bs[3][128 * 32];   // 8 KB per stage
    const int tid = threadIdx.x;
    const int wave = tid >> 6, lane = tid & 63;
    const int row0 = blockIdx.y * 64;
    const int col0 = blockIdx.x * 128;
    const int wr = (wave >> 1) * 32;     // wave's 32-row strip
    const int wc = (wave & 1) * 64;      // wave's 64-col strip

    floatx4 acc[2][4] = {};

    const int srow = lane >> 2;                       // 0..15
    const int sg   = (lane & 3) ^ ((srow >> 1) & 3);  // XOR swizzle
    const int scol = sg * 8;

    // per-thread staging: 1 A-chunk (16 rows), 2 B-chunks
    const unsigned short* Ag  = Abf + (size_t)(row0 + wave * 16 + srow) * 512 + scol;
    const unsigned short* Wg0 = Wbf + (size_t)(col0 + (wave * 2 + 0) * 16 + srow) * 512 + scol;
    const unsigned short* Wg1 = Wbf + (size_t)(col0 + (wave * 2 + 1) * 16 + srow) * 512 + scol;

    char* Al  = (char*)&As[0][0] + wave * 1024;
    char* Bl0 = (char*)&Bs[0][0] + (wave * 2 + 0) * 1024;
    char* Bl1 = (char*)&Bs[0][0] + (wave * 2 + 1) * 1024;

    // prologue: stage k-chunks 0 and 1 into ring slots 0 and 1 (6 loads in flight/wave)
    #pragma unroll
    for (int p = 0; p < 2; ++p) {
        g2lds16(Ag  + p * 32, Al  + p * 4096);
        g2lds16(Wg0 + p * 32, Bl0 + p * 8192);
        g2lds16(Wg1 + p * 32, Bl1 + p * 8192);
    }

    // Main loop: counted vmcnt — never drain to 0 mid-loop (T3+T4).
    // Ring safety: stage of batch it+2 overwrites slot (it-1)%3; all waves'
    // ds_reads of batch it-1 completed (lgkm-waited before their MFMAs)
    // before they reached this barrier.
    #pragma unroll
    for (int it = 0; it < 16; ++it) {
        if (it < 15) asm volatile("s_waitcnt vmcnt(3)" ::: "memory");  // batch `it` landed
        else         asm volatile("s_waitcnt vmcnt(0)" ::: "memory");  // last batch
        __builtin_amdgcn_s_barrier();
        __builtin_amdgcn_sched_barrier(0);   // nothing moves above the barrier
        if (it < 14) {
            const int nb = (it + 2) % 3;
            const int k1 = (it + 2) * 32;
            g2lds16(Ag  + k1, Al  + nb * 4096);
            g2lds16(Wg0 + k1, Bl0 + nb * 8192);
            g2lds16(Wg1 + k1, Bl1 + nb * 8192);
        }
        const int cur = it % 3;
        short8 af[2], bfr[4];
        #pragma unroll
        for (int i = 0; i < 2; i++) {
            int m = wr + i * 16 + (lane & 15);
            int gm = (lane >> 4) ^ ((m >> 1) & 3);
            af[i] = *(const short8*)&As[cur][m * 32 + gm * 8];
        }
        #pragma unroll
        for (int j = 0; j < 4; j++) {
            int n = wc + j * 16 + (lane & 15);
            int gn = (lane >> 4) ^ ((n >> 1) & 3);
            bfr[j] = *(const short8*)&Bs[cur][n * 32 + gn * 8];
        }
        #pragma unroll
        for (int i = 0; i < 2; i++)
            #pragma unroll
            for (int j = 0; j < 4; j++)
                acc[i][j] = __builtin_amdgcn_mfma_f32_16x16x32_bf16(af[i], bfr[j], acc[i][j], 0, 0, 0);
    }

    // epilogue: C/D layout col=lane&15, row=(lane>>4)*4+reg
    if (col0 >= 512) {
        // B/C tile: logical cols 512..543 -> Bm/Cm; cols >=544 are zero padding
        #pragma unroll
        for (int i = 0; i < 2; i++) {
            #pragma unroll
            for (int reg = 0; reg < 4; reg++) {
                int r = row0 + wr + i * 16 + (lane >> 4) * 4 + reg;
                #pragma unroll
                for (int j = 0; j < 4; j++) {
                    int c2 = wc + j * 16 + (lane & 15);   // 0..127 within tile
                    float z = acc[i][j][reg];
                    if (c2 < 16)      Bm[(size_t)r * 16 + c2]        = z + b_B[c2];
                    else if (c2 < 32) Cm[(size_t)r * 16 + (c2 - 16)] = z + b_C[c2 - 16];
                }
            }
        }
        return;
    }

    #pragma unroll
    for (int i = 0; i < 2; i++) {
        #pragma unroll
        for (int reg = 0; reg < 4; reg++) {
            int r = row0 + wr + i * 16 + (lane >> 4) * 4 + reg;
            float lwr = lw[r];
            #pragma unroll
            for (int j = 0; j < 4; j++) {
                int c = col0 + wc + j * 16 + (lane & 15);
                float z = acc[i][j][reg] + bias[c];
                if (mode == 0) {
                    float o = z + lwr * wcol[(size_t)c * wcol_stride];
                    outbf[(size_t)r * 512 + c] = f2bf(o);
                } else {
                    float sp = (z > 15.f) ? z : log1pf(__expf(z));
                    float sg2 = 1.f / (1.f + __expf(-(lwr * wcol[c] + bw[c])));
                    outf[(size_t)r * 512 + c] = sp * sg2;
                }
            }
        }
    }
}

// fast path valid when As[s] == (s+1)*As[0]
__device__ __forceinline__ bool geo_check(const float* As) {
    bool ok = true;
    #pragma unroll
    for (int s = 1; s < 16; s++) {
        float want = (float)(s + 1) * As[0];
        ok = ok && (fabsf(As[s] - want) <= 1e-4f * (float)(s + 1));
    }
    return ok;
}

// ---------------- checkpoint kernel: H for all level-9 nodes ----------------
__global__ __launch_bounds__(256) void ckpt_kernel(
    const unsigned short* __restrict__ x_bf, const float* __restrict__ delta,
    const float* __restrict__ Bm, const float* __restrict__ A_log,
    float* __restrict__ H9)
{
    const int n9 = blockIdx.x;
    const int t = threadIdx.x;
    const int d0 = t, d1 = t + 256;

    float As0[16], As1[16], acc0[16], acc1[16];
    #pragma unroll
    for (int s = 0; s < 16; s++) {
        As0[s] = -__expf(A_log[d0 * 16 + s]);
        As1[s] = -__expf(A_log[d1 * 16 + s]);
        acc0[s] = 0.f; acc1[s] = 0.f;
    }
    const bool fast = geo_check(As0) && geo_check(As1);

    float cum0 = 0.f, cum1 = 0.f;
    int a = CKPT_BASE + n9;
    while (a >= 0) {
        float da0 = delta[(size_t)a * 512 + d0];
        float da1 = delta[(size_t)a * 512 + d1];
        float bx0 = da0 * bf2f(x_bf[(size_t)a * 512 + d0]);
        float bx1 = da1 * bf2f(x_bf[(size_t)a * 512 + d1]);
        if (fast) {
            float r0 = __expf(As0[0] * cum0);
            float r1 = __expf(As1[0] * cum1);
            float pw0 = r0, pw1 = r1;
            #pragma unroll
            for (int s = 0; s < 16; s++) {
                float Bs = Bm[a * 16 + s];
                acc0[s] = fmaf(bx0 * pw0, Bs, acc0[s]);
                acc1[s] = fmaf(bx1 * pw1, Bs, acc1[s]);
                pw0 *= r0; pw1 *= r1;
            }
        } else {
            #pragma unroll
            for (int s = 0; s < 16; s++) {
                float Bs = Bm[a * 16 + s];
                acc0[s] = fmaf(bx0 * __expf(As0[s] * cum0), Bs, acc0[s]);
                acc1[s] = fmaf(bx1 * __expf(As1[s] * cum1), Bs, acc1[s]);
            }
        }
        cum0 += da0; cum1 += da1;
        a = (a - 1) >> 1;
    }

    float* p0 = H9 + ((size_t)n9 * 512 + d0) * 16;
    float* p1 = H9 + ((size_t)n9 * 512 + d1) * 16;
    #pragma unroll
    for (int s = 0; s < 16; s++) { p0[s] = acc0[s]; p1[s] = acc1[s]; }
}

// ---------------- shallow scan (nodes 0..510, levels 0..8): walk + LN ----------------
__global__ __launch_bounds__(256) void scan_shallow(
    const unsigned short* __restrict__ x_bf, const float* __restrict__ delta,
    const float* __restrict__ Bm, const float* __restrict__ Cm,
    const float* __restrict__ A_log, const float* __restrict__ Dv,
    const float* __restrict__ gamma, const float* __restrict__ beta,
    float* __restrict__ out)
{
    const int n = blockIdx.x;
    const int t = threadIdx.x;
    const int d0 = t, d1 = t + 256;

    float As0[16], As1[16], acc0[16], acc1[16];
    #pragma unroll
    for (int s = 0; s < 16; s++) {
        As0[s] = -__expf(A_log[d0 * 16 + s]);
        As1[s] = -__expf(A_log[d1 * 16 + s]);
        acc0[s] = 0.f; acc1[s] = 0.f;
    }
    const bool fast = geo_check(As0) && geo_check(As1);

    float cum0 = 0.f, cum1 = 0.f;
    int a = n;
    while (a >= 0) {
        float da0 = delta[(size_t)a * 512 + d0];
        float da1 = delta[(size_t)a * 512 + d1];
        float bx0 = da0 * bf2f(x_bf[(size_t)a * 512 + d0]);
        float bx1 = da1 * bf2f(x_bf[(size_t)a * 512 + d1]);
        if (fast) {
            float r0 = __expf(As0[0] * cum0);
            float r1 = __expf(As1[0] * cum1);
            float pw0 = r0, pw1 = r1;
            #pragma unroll
            for (int s = 0; s < 16; s++) {
                float Bs = Bm[a * 16 + s];
                acc0[s] = fmaf(bx0 * pw0, Bs, acc0[s]);
                acc1[s] = fmaf(bx1 * pw1, Bs, acc1[s]);
                pw0 *= r0; pw1 *= r1;
            }
        } else {
            #pragma unroll
            for (int s = 0; s < 16; s++) {
                float Bs = Bm[a * 16 + s];
                acc0[s] = fmaf(bx0 * __expf(As0[s] * cum0), Bs, acc0[s]);
                acc1[s] = fmaf(bx1 * __expf(As1[s] * cum1), Bs, acc1[s]);
            }
        }
        cum0 += da0; cum1 += da1;
        a = (a - 1) >> 1;
    }

    float xn0 = bf2f(x_bf[(size_t)n * 512 + d0]);
    float xn1 = bf2f(x_bf[(size_t)n * 512 + d1]);
    float y0 = Dv[d0] * xn0, y1 = Dv[d1] * xn1;
    #pragma unroll
    for (int s = 0; s < 16; s++) {
        float Cs = Cm[(size_t)n * 16 + s];
        y0 += Cs * acc0[s];
        y1 += Cs * acc1[s];
    }

    float s1 = y0 + y1;
    float s2 = y0 * y0 + y1 * y1;
    #pragma unroll
    for (int off = 32; off > 0; off >>= 1) {
        s1 += __shfl_xor(s1, off);
        s2 += __shfl_xor(s2, off);
    }
    __shared__ float red[8];
    int wid = t >> 6, lane = t & 63;
    if (lane == 0) { red[wid] = s1; red[wid + 4] = s2; }
    __syncthreads();
    float S1 = red[0] + red[1] + red[2] + red[3];
    float S2 = red[4] + red[5] + red[6] + red[7];
    float mu = S1 * (1.f / 512.f);
    float var = S2 * (1.f / 512.f) - mu * mu;
    float inv = rsqrtf(var + 1e-5f);
    out[(size_t)n * 512 + d0] = (y0 - mu) * inv * gamma[d0] + beta[d0];
    out[(size_t)n * 512 + d1] = (y1 - mu) * inv * gamma[d1] + beta[d1];
}

// ---------------- deep scan: one block per level-9 subtree, DFS forward sweep ----------------
__global__ __launch_bounds__(512) void scan_deep(
    const unsigned short* __restrict__ x_bf, const float* __restrict__ delta,
    const float* __restrict__ Bm, const float* __restrict__ Cm,
    const float* __restrict__ H9,
    const float* __restrict__ A_log, const float* __restrict__ Dv,
    const float* __restrict__ gamma, const float* __restrict__ beta,
    float* __restrict__ out)
{
    __shared__ float Y[31][512];
    __shared__ int nid[31];
    const int p = blockIdx.x;
    const int d = threadIdx.x;
    const int a9 = CKPT_BASE + p;

    float As0 = -__expf(A_log[d * 16]);
    bool fast = true;
    #pragma unroll
    for (int s = 1; s < 16; s++) {
        float As = -__expf(A_log[d * 16 + s]);
        fast = fast && (fabsf(As - (float)(s + 1) * As0) <= 1e-4f * (float)(s + 1));
    }

    float H9v[16];
    #pragma unroll
    for (int s = 0; s < 16; s++) H9v[s] = H9[((size_t)p * 512 + d) * 16 + s];

    {
        float xv = bf2f(x_bf[(size_t)a9 * 512 + d]);
        float y = Dv[d] * xv;
        #pragma unroll
        for (int s = 0; s < 16; s++) y = fmaf(Cm[(size_t)a9 * 16 + s], H9v[s], y);
        Y[0][d] = y;
        if (d == 0) nid[0] = a9;
    }

    auto step = [&](int n, const float* Hp, float* Hc, int slot) {
        float dlt = delta[(size_t)n * 512 + d];
        float xv = bf2f(x_bf[(size_t)n * 512 + d]);
        float bx = dlt * xv;
        const float* Bn = Bm + (size_t)n * 16;
        const float* Cn = Cm + (size_t)n * 16;
        float y = Dv[d] * xv;
        if (fast) {
            float r = __expf(As0 * dlt);
            float pw = r;
            #pragma unroll
            for (int s = 0; s < 16; s++) {
                Hc[s] = fmaf(pw, Hp[s], bx * Bn[s]);
                y = fmaf(Cn[s], Hc[s], y);
                pw *= r;
            }
        } else {
            #pragma unroll
            for (int s = 0; s < 16; s++) {
                float Ab = __expf(dlt * (-__expf(A_log[d * 16 + s])));
                Hc[s] = fmaf(Ab, Hp[s], bx * Bn[s]);
                y = fmaf(Cn[s], Hc[s], y);
            }
        }
        Y[slot][d] = y;
        if (d == 0) nid[slot] = n;
    };

    float H10[16], H11[16], H12[16], H13[16];
    int slot = 1;
    #pragma unroll
    for (int c0 = 0; c0 < 2; c0++) {
        int n10 = 2 * a9 + 1 + c0;
        step(n10, H9v, H10, slot++);
        #pragma unroll
        for (int c1 = 0; c1 < 2; c1++) {
            int n11 = 2 * n10 + 1 + c1;
            step(n11, H10, H11, slot++);
            #pragma unroll
            for (int c2 = 0; c2 < 2; c2++) {
                int n12 = 2 * n11 + 1 + c2;
                step(n12, H11, H12, slot++);
                #pragma unroll
                for (int c3 = 0; c3 < 2; c3++) {
                    int n13 = 2 * n12 + 1 + c3;
                    step(n13, H12, H13, slot++);
                }
            }
        }
    }
    __syncthreads();

    const int w = d >> 6, lane = d & 63;
    for (int i = w; i < 31; i += 8) {
        int n = nid[i];
        float v[8]; float s1 = 0.f, s2 = 0.f;
        #pragma unroll
        for (int k = 0; k < 8; k++) {
            v[k] = Y[i][lane + 64 * k];
            s1 += v[k]; s2 += v[k] * v[k];
        }
        #pragma unroll
        for (int off = 32; off > 0; off >>= 1) {
            s1 += __shfl_xor(s1, off);
            s2 += __shfl_xor(s2, off);
        }
        float mu = s1 * (1.f / 512.f);
        float inv = rsqrtf(s2 * (1.f / 512.f) - mu * mu + 1e-5f);
        #pragma unroll
        for (int k = 0; k < 8; k++) {
            int ch = lane + 64 * k;
            out[(size_t)n * 512 + ch] = (v[k] - mu) * inv * gamma[ch] + beta[ch];
        }
    }
}

extern "C" void kernel_launch(void* const* d_in, const int* in_sizes, int n_in,
                              void* d_out, int out_size, void* d_ws, size_t ws_size,
                              hipStream_t stream) {
    const float* s_in   = (const float*)d_in[0];
    const float* w      = (const float*)d_in[1];
    const float* W_in    = (const float*)d_in[4];
    const float* b_in    = (const float*)d_in[5];
    const float* W_delta = (const float*)d_in[6];
    const float* b_delta = (const float*)d_in[7];
    const float* W_w     = (const float*)d_in[8];
    const float* b_w     = (const float*)d_in[9];
    const float* A_log   = (const float*)d_in[10];
    const float* Dv      = (const float*)d_in[11];
    const float* W_B     = (const float*)d_in[12];
    const float* b_B     = (const float*)d_in[13];
    const float* W_C     = (const float*)d_in[14];
    const float* b_C     = (const float*)d_in[15];
    const float* gamma   = (const float*)d_in[16];
    const float* beta    = (const float*)d_in[17];
    float* out = (float*)d_out;

    const int Nn = in_sizes[1];           // 16383

    float* ws    = (float*)d_ws;
    float* lw    = ws;                                      // 16384
    float* delta = lw + MPAD;                               // 16384*512 fp32
    float* Bm    = delta + (size_t)MPAD * 512;              // 16384*16
    float* Cm    = Bm + (size_t)MPAD * 16;                  // 16384*16
    float* H9    = Cm + (size_t)MPAD * 16;                  // 512*512*16
    unsigned short* s_bf  = (unsigned short*)(H9 + (size_t)N_CKPT * 512 * 16);  // 16384*512
    unsigned short* x_bf  = s_bf + (size_t)MPAD * 512;      // 16384*512
    unsigned short* Win_bf = x_bf + (size_t)MPAD * 512;     // 512*512
    unsigned short* Wd_bf  = Win_bf + 512 * 512;            // 640*512 (delta + B + C + pad)

    prep_kernel<<<MPAD + 1024 + 128, 256, 0, stream>>>(s_in, w, W_in, W_delta, W_B, W_C,
                                                       s_bf, lw, Win_bf, Wd_bf, Nn);

    dim3 g1(4, 256);   // 128-col x 64-row tiles -> 1024 blocks
    gemm_mfma<<<g1, 256, 0, stream>>>(s_bf, Win_bf, nullptr, x_bf,
                                      b_in, lw, W_in + 512, 513, nullptr,
                                      nullptr, nullptr, nullptr, nullptr, 0);
    dim3 g2(5, 256);   // 5th col tile = B/C columns
    gemm_mfma<<<g2, 256, 0, stream>>>(x_bf, Wd_bf, delta, nullptr,
                                      b_delta, lw, W_w, 1, b_w,
                                      b_B, b_C, Bm, Cm, 1);

    ckpt_kernel<<<N_CKPT, 256, 0, stream>>>(x_bf, delta, Bm, A_log, H9);

    scan_shallow<<<CKPT_BASE, 256, 0, stream>>>(x_bf, delta, Bm, Cm, A_log, Dv,
                                                gamma, beta, out);

    scan_deep<<<N_CKPT, 512, 0, stream>>>(x_bf, delta, Bm, Cm, H9, A_log, Dv,
                                          gamma, beta, out);
}

// Round 2
// 244.024 us; speedup vs baseline: 1.0930x; 1.0930x over previous
//
#include <hip/hip_runtime.h>
#include <hip/hip_bf16.h>
#include <math.h>

#define D_SSM 512
#define D_STATE 16
#define CKPT_BASE 511     // first index of level 9
#define CKPT_END 1023     // first index of level 10
#define N_CKPT 512        // nodes at level 9
#define MPAD 16384

typedef __attribute__((ext_vector_type(8))) short short8;
typedef __attribute__((ext_vector_type(4))) float floatx4;

__device__ __forceinline__ unsigned short f2bf(float f) {
    unsigned int u = __float_as_uint(f);
    unsigned int r = (u + 0x7fffu + ((u >> 16) & 1u)) >> 16;
    return (unsigned short)r;
}
__device__ __forceinline__ float bf2f(unsigned short u) {
    return __uint_as_float(((unsigned int)u) << 16);
}
__device__ __forceinline__ void g2lds16(const void* g, void* l) {
    __builtin_amdgcn_global_load_lds(
        (const __attribute__((address_space(1))) void*)g,
        (__attribute__((address_space(3))) void*)l, 16, 0, 0);
}

// ---------------- prep: cast s/W_in/W_delta to bf16; W2 = [W_delta; W_B; W_C; 0] (640 rows) ----------------
__global__ __launch_bounds__(256) void prep_kernel(
    const float* __restrict__ s, const float* __restrict__ w,
    const float* __restrict__ W_in, const float* __restrict__ W_delta,
    const float* __restrict__ W_B, const float* __restrict__ W_C,
    unsigned short* __restrict__ s_bf, float* __restrict__ lw,
    unsigned short* __restrict__ Win_bf, unsigned short* __restrict__ Wd_bf,
    int Nn)
{
    const int b = blockIdx.x, t = threadIdx.x;
    if (b < MPAD) {
        unsigned int pack = 0;
        if (b < Nn) {
            float2 sv = *(const float2*)(s + (size_t)b * 512 + t * 2);
            pack = (unsigned int)f2bf(sv.x) | ((unsigned int)f2bf(sv.y) << 16);
        }
        *(unsigned int*)(s_bf + (size_t)b * 512 + t * 2) = pack;
        if (t == 0) lw[b] = (b < Nn) ? logf(w[b] + 1e-6f) : 0.f;
    } else if (b < MPAD + 512) {
        int c = b - MPAD;
        float a0 = W_in[(size_t)c * 513 + t * 2];
        float a1 = W_in[(size_t)c * 513 + t * 2 + 1];
        *(unsigned int*)(Win_bf + (size_t)c * 512 + t * 2) =
            (unsigned int)f2bf(a0) | ((unsigned int)f2bf(a1) << 16);
    } else if (b < MPAD + 1024) {
        int c = b - MPAD - 512;
        float2 wv = *(const float2*)(W_delta + (size_t)c * 512 + t * 2);
        *(unsigned int*)(Wd_bf + (size_t)c * 512 + t * 2) =
            (unsigned int)f2bf(wv.x) | ((unsigned int)f2bf(wv.y) << 16);
    } else {
        // rows 512..639 of W2: 0..15 = W_B, 16..31 = W_C, rest zero padding
        int c = b - MPAD - 1024;   // 0..127
        float2 wv; wv.x = 0.f; wv.y = 0.f;
        if (c < 16)      wv = *(const float2*)(W_B + (size_t)c * 512 + t * 2);
        else if (c < 32) wv = *(const float2*)(W_C + (size_t)(c - 16) * 512 + t * 2);
        *(unsigned int*)(Wd_bf + (size_t)(512 + c) * 512 + t * 2) =
            (unsigned int)f2bf(wv.x) | ((unsigned int)f2bf(wv.y) << 16);
    }
}

// ---------------- bf16 MFMA GEMM, 128x128 tile (m97 structure), double-buffered LDS ----------------
// 4 waves, each owns a 64x64 sub-tile (4x4 fragments, 16 MFMA per BK=32 K-step).
// mode 0: o = z + bias[c] + lw[r]*wcol[c*wcol_stride]; store bf16 -> outbf
// mode 1: o = softplus(z+bias[c]) * sigmoid(lw[r]*wcol[c]+bw[c]); store fp32 -> outf
// col tile with col0 >= 512 (mode 1 only): cols 512..543 are B/C -> Bm/Cm
__global__ __launch_bounds__(256) void gemm_mfma(
    const unsigned short* __restrict__ Abf,   // [16384][512] bf16
    const unsigned short* __restrict__ Wbf,   // [512 or 640][512] bf16
    float* __restrict__ outf,
    unsigned short* __restrict__ outbf,
    const float* __restrict__ bias,
    const float* __restrict__ lw,
    const float* __restrict__ wcol, int wcol_stride,
    const float* __restrict__ bw,
    const float* __restrict__ b_B, const float* __restrict__ b_C,
    float* __restrict__ Bm, float* __restrict__ Cm,
    int mode)
{
    __shared__ __align__(16) short As[2][128 * 32];   // 8 KB per buffer
    __shared__ __align__(16) short Bs[2][128 * 32];   // 8 KB per buffer
    const int tid = threadIdx.x;
    const int wave = tid >> 6, lane = tid & 63;
    const int row0 = blockIdx.y * 128;
    const int col0 = blockIdx.x * 128;
    const int wr = (wave >> 1) * 64;     // wave's 64-row strip
    const int wc = (wave & 1) * 64;      // wave's 64-col strip

    floatx4 acc[4][4] = {};

    const int srow = lane >> 2;                       // 0..15
    const int sg   = (lane & 3) ^ ((srow >> 1) & 3);  // XOR swizzle
    const int scol = sg * 8;

    // per-wave staging: A-chunks {wave, wave+4} (16 rows each), same for B
    const unsigned short* Ag = Abf + (size_t)(row0 + wave * 16 + srow) * 512 + scol;
    const unsigned short* Wg = Wbf + (size_t)(col0 + wave * 16 + srow) * 512 + scol;
    char* Al = (char*)&As[0][0] + wave * 1024;
    char* Bl = (char*)&Bs[0][0] + wave * 1024;

    #define STAGE(buf, k0)                                              \
        do {                                                            \
            g2lds16(Ag + (k0),            Al + (buf) * 8192);           \
            g2lds16(Ag + 64 * 512 + (k0), Al + (buf) * 8192 + 4096);    \
            g2lds16(Wg + (k0),            Bl + (buf) * 8192);           \
            g2lds16(Wg + 64 * 512 + (k0), Bl + (buf) * 8192 + 4096);    \
        } while (0)

    STAGE(0, 0);
    __syncthreads();

    for (int it = 0; it < 16; ++it) {
        const int cur = it & 1;
        if (it < 15) STAGE(cur ^ 1, (it + 1) * 32);

        short8 af[4], bfr[4];
        #pragma unroll
        for (int i = 0; i < 4; i++) {
            int m = wr + i * 16 + (lane & 15);
            int gm = (lane >> 4) ^ ((m >> 1) & 3);
            af[i] = *(const short8*)&As[cur][m * 32 + gm * 8];
        }
        #pragma unroll
        for (int j = 0; j < 4; j++) {
            int n = wc + j * 16 + (lane & 15);
            int gn = (lane >> 4) ^ ((n >> 1) & 3);
            bfr[j] = *(const short8*)&Bs[cur][n * 32 + gn * 8];
        }
        #pragma unroll
        for (int i = 0; i < 4; i++)
            #pragma unroll
            for (int j = 0; j < 4; j++)
                acc[i][j] = __builtin_amdgcn_mfma_f32_16x16x32_bf16(af[i], bfr[j], acc[i][j], 0, 0, 0);
        __syncthreads();   // drains prefetch vmcnt + guards buffer reuse
    }
    #undef STAGE

    // epilogue: C/D layout col=lane&15, row=(lane>>4)*4+reg
    if (col0 >= 512) {
        // B/C tile: logical cols 512..543 -> Bm/Cm; cols >=544 are zero padding
        #pragma unroll
        for (int i = 0; i < 4; i++) {
            #pragma unroll
            for (int reg = 0; reg < 4; reg++) {
                int r = row0 + wr + i * 16 + (lane >> 4) * 4 + reg;
                #pragma unroll
                for (int j = 0; j < 4; j++) {
                    int c2 = wc + j * 16 + (lane & 15);   // 0..127 within tile
                    float z = acc[i][j][reg];
                    if (c2 < 16)      Bm[(size_t)r * 16 + c2]        = z + b_B[c2];
                    else if (c2 < 32) Cm[(size_t)r * 16 + (c2 - 16)] = z + b_C[c2 - 16];
                }
            }
        }
        return;
    }

    #pragma unroll
    for (int i = 0; i < 4; i++) {
        #pragma unroll
        for (int reg = 0; reg < 4; reg++) {
            int r = row0 + wr + i * 16 + (lane >> 4) * 4 + reg;
            float lwr = lw[r];
            #pragma unroll
            for (int j = 0; j < 4; j++) {
                int c = col0 + wc + j * 16 + (lane & 15);
                float z = acc[i][j][reg] + bias[c];
                if (mode == 0) {
                    float o = z + lwr * wcol[(size_t)c * wcol_stride];
                    outbf[(size_t)r * 512 + c] = f2bf(o);
                } else {
                    // fast softplus: __logf (v_log based) instead of libm log1pf
                    float sp = (z > 15.f) ? z : __logf(1.f + __expf(z));
                    // fast sigmoid: v_rcp instead of full-precision fp32 divide
                    float sg2 = __builtin_amdgcn_rcpf(1.f + __expf(-(lwr * wcol[c] + bw[c])));
                    outf[(size_t)r * 512 + c] = sp * sg2;
                }
            }
        }
    }
}

// fast path valid when As[s] == (s+1)*As[0]
__device__ __forceinline__ bool geo_check(const float* As) {
    bool ok = true;
    #pragma unroll
    for (int s = 1; s < 16; s++) {
        float want = (float)(s + 1) * As[0];
        ok = ok && (fabsf(As[s] - want) <= 1e-4f * (float)(s + 1));
    }
    return ok;
}

// ---------------- checkpoint kernel: H for all level-9 nodes ----------------
__global__ __launch_bounds__(256) void ckpt_kernel(
    const unsigned short* __restrict__ x_bf, const float* __restrict__ delta,
    const float* __restrict__ Bm, const float* __restrict__ A_log,
    float* __restrict__ H9)
{
    const int n9 = blockIdx.x;
    const int t = threadIdx.x;
    const int d0 = t, d1 = t + 256;

    float As0[16], As1[16], acc0[16], acc1[16];
    #pragma unroll
    for (int s = 0; s < 16; s++) {
        As0[s] = -__expf(A_log[d0 * 16 + s]);
        As1[s] = -__expf(A_log[d1 * 16 + s]);
        acc0[s] = 0.f; acc1[s] = 0.f;
    }
    const bool fast = geo_check(As0) && geo_check(As1);

    float cum0 = 0.f, cum1 = 0.f;
    int a = CKPT_BASE + n9;
    while (a >= 0) {
        float da0 = delta[(size_t)a * 512 + d0];
        float da1 = delta[(size_t)a * 512 + d1];
        float bx0 = da0 * bf2f(x_bf[(size_t)a * 512 + d0]);
        float bx1 = da1 * bf2f(x_bf[(size_t)a * 512 + d1]);
        if (fast) {
            float r0 = __expf(As0[0] * cum0);
            float r1 = __expf(As1[0] * cum1);
            float pw0 = r0, pw1 = r1;
            #pragma unroll
            for (int s = 0; s < 16; s++) {
                float Bs = Bm[a * 16 + s];
                acc0[s] = fmaf(bx0 * pw0, Bs, acc0[s]);
                acc1[s] = fmaf(bx1 * pw1, Bs, acc1[s]);
                pw0 *= r0; pw1 *= r1;
            }
        } else {
            #pragma unroll
            for (int s = 0; s < 16; s++) {
                float Bs = Bm[a * 16 + s];
                acc0[s] = fmaf(bx0 * __expf(As0[s] * cum0), Bs, acc0[s]);
                acc1[s] = fmaf(bx1 * __expf(As1[s] * cum1), Bs, acc1[s]);
            }
        }
        cum0 += da0; cum1 += da1;
        a = (a - 1) >> 1;
    }

    float* p0 = H9 + ((size_t)n9 * 512 + d0) * 16;
    float* p1 = H9 + ((size_t)n9 * 512 + d1) * 16;
    #pragma unroll
    for (int s = 0; s < 16; s++) { p0[s] = acc0[s]; p1[s] = acc1[s]; }
}

// ---------------- shallow scan (nodes 0..510, levels 0..8): walk + LN ----------------
__global__ __launch_bounds__(256) void scan_shallow(
    const unsigned short* __restrict__ x_bf, const float* __restrict__ delta,
    const float* __restrict__ Bm, const float* __restrict__ Cm,
    const float* __restrict__ A_log, const float* __restrict__ Dv,
    const float* __restrict__ gamma, const float* __restrict__ beta,
    float* __restrict__ out)
{
    const int n = blockIdx.x;
    const int t = threadIdx.x;
    const int d0 = t, d1 = t + 256;

    float As0[16], As1[16], acc0[16], acc1[16];
    #pragma unroll
    for (int s = 0; s < 16; s++) {
        As0[s] = -__expf(A_log[d0 * 16 + s]);
        As1[s] = -__expf(A_log[d1 * 16 + s]);
        acc0[s] = 0.f; acc1[s] = 0.f;
    }
    const bool fast = geo_check(As0) && geo_check(As1);

    float cum0 = 0.f, cum1 = 0.f;
    int a = n;
    while (a >= 0) {
        float da0 = delta[(size_t)a * 512 + d0];
        float da1 = delta[(size_t)a * 512 + d1];
        float bx0 = da0 * bf2f(x_bf[(size_t)a * 512 + d0]);
        float bx1 = da1 * bf2f(x_bf[(size_t)a * 512 + d1]);
        if (fast) {
            float r0 = __expf(As0[0] * cum0);
            float r1 = __expf(As1[0] * cum1);
            float pw0 = r0, pw1 = r1;
            #pragma unroll
            for (int s = 0; s < 16; s++) {
                float Bs = Bm[a * 16 + s];
                acc0[s] = fmaf(bx0 * pw0, Bs, acc0[s]);
                acc1[s] = fmaf(bx1 * pw1, Bs, acc1[s]);
                pw0 *= r0; pw1 *= r1;
            }
        } else {
            #pragma unroll
            for (int s = 0; s < 16; s++) {
                float Bs = Bm[a * 16 + s];
                acc0[s] = fmaf(bx0 * __expf(As0[s] * cum0), Bs, acc0[s]);
                acc1[s] = fmaf(bx1 * __expf(As1[s] * cum1), Bs, acc1[s]);
            }
        }
        cum0 += da0; cum1 += da1;
        a = (a - 1) >> 1;
    }

    float xn0 = bf2f(x_bf[(size_t)n * 512 + d0]);
    float xn1 = bf2f(x_bf[(size_t)n * 512 + d1]);
    float y0 = Dv[d0] * xn0, y1 = Dv[d1] * xn1;
    #pragma unroll
    for (int s = 0; s < 16; s++) {
        float Cs = Cm[(size_t)n * 16 + s];
        y0 += Cs * acc0[s];
        y1 += Cs * acc1[s];
    }

    float s1 = y0 + y1;
    float s2 = y0 * y0 + y1 * y1;
    #pragma unroll
    for (int off = 32; off > 0; off >>= 1) {
        s1 += __shfl_xor(s1, off);
        s2 += __shfl_xor(s2, off);
    }
    __shared__ float red[8];
    int wid = t >> 6, lane = t & 63;
    if (lane == 0) { red[wid] = s1; red[wid + 4] = s2; }
    __syncthreads();
    float S1 = red[0] + red[1] + red[2] + red[3];
    float S2 = red[4] + red[5] + red[6] + red[7];
    float mu = S1 * (1.f / 512.f);
    float var = S2 * (1.f / 512.f) - mu * mu;
    float inv = rsqrtf(var + 1e-5f);
    out[(size_t)n * 512 + d0] = (y0 - mu) * inv * gamma[d0] + beta[d0];
    out[(size_t)n * 512 + d1] = (y1 - mu) * inv * gamma[d1] + beta[d1];
}

// ---------------- deep scan: one block per level-9 subtree, DFS forward sweep ----------------
__global__ __launch_bounds__(512) void scan_deep(
    const unsigned short* __restrict__ x_bf, const float* __restrict__ delta,
    const float* __restrict__ Bm, const float* __restrict__ Cm,
    const float* __restrict__ H9,
    const float* __restrict__ A_log, const float* __restrict__ Dv,
    const float* __restrict__ gamma, const float* __restrict__ beta,
    float* __restrict__ out)
{
    __shared__ float Y[31][512];
    __shared__ int nid[31];
    const int p = blockIdx.x;
    const int d = threadIdx.x;
    const int a9 = CKPT_BASE + p;

    float As0 = -__expf(A_log[d * 16]);
    bool fast = true;
    #pragma unroll
    for (int s = 1; s < 16; s++) {
        float As = -__expf(A_log[d * 16 + s]);
        fast = fast && (fabsf(As - (float)(s + 1) * As0) <= 1e-4f * (float)(s + 1));
    }

    float H9v[16];
    #pragma unroll
    for (int s = 0; s < 16; s++) H9v[s] = H9[((size_t)p * 512 + d) * 16 + s];

    {
        float xv = bf2f(x_bf[(size_t)a9 * 512 + d]);
        float y = Dv[d] * xv;
        #pragma unroll
        for (int s = 0; s < 16; s++) y = fmaf(Cm[(size_t)a9 * 16 + s], H9v[s], y);
        Y[0][d] = y;
        if (d == 0) nid[0] = a9;
    }

    auto step = [&](int n, const float* Hp, float* Hc, int slot) {
        float dlt = delta[(size_t)n * 512 + d];
        float xv = bf2f(x_bf[(size_t)n * 512 + d]);
        float bx = dlt * xv;
        const float* Bn = Bm + (size_t)n * 16;
        const float* Cn = Cm + (size_t)n * 16;
        float y = Dv[d] * xv;
        if (fast) {
            float r = __expf(As0 * dlt);
            float pw = r;
            #pragma unroll
            for (int s = 0; s < 16; s++) {
                Hc[s] = fmaf(pw, Hp[s], bx * Bn[s]);
                y = fmaf(Cn[s], Hc[s], y);
                pw *= r;
            }
        } else {
            #pragma unroll
            for (int s = 0; s < 16; s++) {
                float Ab = __expf(dlt * (-__expf(A_log[d * 16 + s])));
                Hc[s] = fmaf(Ab, Hp[s], bx * Bn[s]);
                y = fmaf(Cn[s], Hc[s], y);
            }
        }
        Y[slot][d] = y;
        if (d == 0) nid[slot] = n;
    };

    float H10[16], H11[16], H12[16], H13[16];
    int slot = 1;
    #pragma unroll
    for (int c0 = 0; c0 < 2; c0++) {
        int n10 = 2 * a9 + 1 + c0;
        step(n10, H9v, H10, slot++);
        #pragma unroll
        for (int c1 = 0; c1 < 2; c1++) {
            int n11 = 2 * n10 + 1 + c1;
            step(n11, H10, H11, slot++);
            #pragma unroll
            for (int c2 = 0; c2 < 2; c2++) {
                int n12 = 2 * n11 + 1 + c2;
                step(n12, H11, H12, slot++);
                #pragma unroll
                for (int c3 = 0; c3 < 2; c3++) {
                    int n13 = 2 * n12 + 1 + c3;
                    step(n13, H12, H13, slot++);
                }
            }
        }
    }
    __syncthreads();

    const int w = d >> 6, lane = d & 63;
    for (int i = w; i < 31; i += 8) {
        int n = nid[i];
        float v[8]; float s1 = 0.f, s2 = 0.f;
        #pragma unroll
        for (int k = 0; k < 8; k++) {
            v[k] = Y[i][lane + 64 * k];
            s1 += v[k]; s2 += v[k] * v[k];
        }
        #pragma unroll
        for (int off = 32; off > 0; off >>= 1) {
            s1 += __shfl_xor(s1, off);
            s2 += __shfl_xor(s2, off);
        }
        float mu = s1 * (1.f / 512.f);
        float inv = rsqrtf(s2 * (1.f / 512.f) - mu * mu + 1e-5f);
        #pragma unroll
        for (int k = 0; k < 8; k++) {
            int ch = lane + 64 * k;
            out[(size_t)n * 512 + ch] = (v[k] - mu) * inv * gamma[ch] + beta[ch];
        }
    }
}

extern "C" void kernel_launch(void* const* d_in, const int* in_sizes, int n_in,
                              void* d_out, int out_size, void* d_ws, size_t ws_size,
                              hipStream_t stream) {
    const float* s_in   = (const float*)d_in[0];
    const float* w      = (const float*)d_in[1];
    const float* W_in    = (const float*)d_in[4];
    const float* b_in    = (const float*)d_in[5];
    const float* W_delta = (const float*)d_in[6];
    const float* b_delta = (const float*)d_in[7];
    const float* W_w     = (const float*)d_in[8];
    const float* b_w     = (const float*)d_in[9];
    const float* A_log   = (const float*)d_in[10];
    const float* Dv      = (const float*)d_in[11];
    const float* W_B     = (const float*)d_in[12];
    const float* b_B     = (const float*)d_in[13];
    const float* W_C     = (const float*)d_in[14];
    const float* b_C     = (const float*)d_in[15];
    const float* gamma   = (const float*)d_in[16];
    const float* beta    = (const float*)d_in[17];
    float* out = (float*)d_out;

    const int Nn = in_sizes[1];           // 16383

    float* ws    = (float*)d_ws;
    float* lw    = ws;                                      // 16384
    float* delta = lw + MPAD;                               // 16384*512 fp32
    float* Bm    = delta + (size_t)MPAD * 512;              // 16384*16
    float* Cm    = Bm + (size_t)MPAD * 16;                  // 16384*16
    float* H9    = Cm + (size_t)MPAD * 16;                  // 512*512*16
    unsigned short* s_bf  = (unsigned short*)(H9 + (size_t)N_CKPT * 512 * 16);  // 16384*512
    unsigned short* x_bf  = s_bf + (size_t)MPAD * 512;      // 16384*512
    unsigned short* Win_bf = x_bf + (size_t)MPAD * 512;     // 512*512
    unsigned short* Wd_bf  = Win_bf + 512 * 512;            // 640*512 (delta + B + C + pad)

    prep_kernel<<<MPAD + 1024 + 128, 256, 0, stream>>>(s_in, w, W_in, W_delta, W_B, W_C,
                                                       s_bf, lw, Win_bf, Wd_bf, Nn);

    dim3 g1(4, 128);   // 128-col x 128-row tiles -> 512 blocks
    gemm_mfma<<<g1, 256, 0, stream>>>(s_bf, Win_bf, nullptr, x_bf,
                                      b_in, lw, W_in + 512, 513, nullptr,
                                      nullptr, nullptr, nullptr, nullptr, 0);
    dim3 g2(5, 128);   // 5th col tile = B/C columns
    gemm_mfma<<<g2, 256, 0, stream>>>(x_bf, Wd_bf, delta, nullptr,
                                      b_delta, lw, W_w, 1, b_w,
                                      b_B, b_C, Bm, Cm, 1);

    ckpt_kernel<<<N_CKPT, 256, 0, stream>>>(x_bf, delta, Bm, A_log, H9);

    scan_shallow<<<CKPT_BASE, 256, 0, stream>>>(x_bf, delta, Bm, Cm, A_log, Dv,
                                                gamma, beta, out);

    scan_deep<<<N_CKPT, 512, 0, stream>>>(x_bf, delta, Bm, Cm, H9, A_log, Dv,
                                          gamma, beta, out);
}

// Round 3
// 225.621 us; speedup vs baseline: 1.1822x; 1.0816x over previous
//
#include <hip/hip_runtime.h>
#include <hip/hip_bf16.h>
#include <math.h>

#define D_SSM 512
#define D_STATE 16
#define CKPT_BASE 511     // first index of level 9
#define N_CKPT 512        // nodes at level 9
#define MPAD 16384

typedef __attribute__((ext_vector_type(8))) short short8;
typedef __attribute__((ext_vector_type(4))) float floatx4;

__device__ __forceinline__ unsigned short f2bf(float f) {
    unsigned int u = __float_as_uint(f);
    unsigned int r = (u + 0x7fffu + ((u >> 16) & 1u)) >> 16;
    return (unsigned short)r;
}
__device__ __forceinline__ float bf2f(unsigned short u) {
    return __uint_as_float(((unsigned int)u) << 16);
}
__device__ __forceinline__ void g2lds16(const void* g, void* l) {
    __builtin_amdgcn_global_load_lds(
        (const __attribute__((address_space(1))) void*)g,
        (__attribute__((address_space(3))) void*)l, 16, 0, 0);
}

// ---------------- prep: cast s/W_in/W_delta to bf16; W2 = [W_delta; W_B; W_C; 0] (640 rows) ----------------
__global__ __launch_bounds__(256) void prep_kernel(
    const float* __restrict__ s, const float* __restrict__ w,
    const float* __restrict__ W_in, const float* __restrict__ W_delta,
    const float* __restrict__ W_B, const float* __restrict__ W_C,
    unsigned short* __restrict__ s_bf, float* __restrict__ lw,
    unsigned short* __restrict__ Win_bf, unsigned short* __restrict__ Wd_bf,
    int Nn)
{
    const int b = blockIdx.x, t = threadIdx.x;
    if (b < MPAD) {
        unsigned int pack = 0;
        if (b < Nn) {
            float2 sv = *(const float2*)(s + (size_t)b * 512 + t * 2);
            pack = (unsigned int)f2bf(sv.x) | ((unsigned int)f2bf(sv.y) << 16);
        }
        *(unsigned int*)(s_bf + (size_t)b * 512 + t * 2) = pack;
        if (t == 0) lw[b] = (b < Nn) ? logf(w[b] + 1e-6f) : 0.f;
    } else if (b < MPAD + 512) {
        int c = b - MPAD;
        float a0 = W_in[(size_t)c * 513 + t * 2];
        float a1 = W_in[(size_t)c * 513 + t * 2 + 1];
        *(unsigned int*)(Win_bf + (size_t)c * 512 + t * 2) =
            (unsigned int)f2bf(a0) | ((unsigned int)f2bf(a1) << 16);
    } else if (b < MPAD + 1024) {
        int c = b - MPAD - 512;
        float2 wv = *(const float2*)(W_delta + (size_t)c * 512 + t * 2);
        *(unsigned int*)(Wd_bf + (size_t)c * 512 + t * 2) =
            (unsigned int)f2bf(wv.x) | ((unsigned int)f2bf(wv.y) << 16);
    } else {
        // rows 512..639 of W2: 0..15 = W_B, 16..31 = W_C, rest zero padding
        int c = b - MPAD - 1024;   // 0..127
        float2 wv; wv.x = 0.f; wv.y = 0.f;
        if (c < 16)      wv = *(const float2*)(W_B + (size_t)c * 512 + t * 2);
        else if (c < 32) wv = *(const float2*)(W_C + (size_t)(c - 16) * 512 + t * 2);
        *(unsigned int*)(Wd_bf + (size_t)(512 + c) * 512 + t * 2) =
            (unsigned int)f2bf(wv.x) | ((unsigned int)f2bf(wv.y) << 16);
    }
}

// ---------------- bf16 MFMA GEMM, 128x128 tile (m97 structure), double-buffered LDS ----------------
// 4 waves, each owns a 64x64 sub-tile (4x4 fragments, 16 MFMA per BK=32 K-step).
// XCD-chunked block swizzle (T1): each XCD's L2 keeps a contiguous set of A row-panels.
// mode 0: o = z + bias[c] + lw[r]*wcol[c*wcol_stride]; store bf16 -> outbf
// mode 1: o = softplus(z+bias[c]) * sigmoid(lw[r]*wcol[c]+bw[c]); store fp32 -> outf
// col tile with col0 >= 512 (mode 1 only): cols 512..543 are B/C -> Bm/Cm
__global__ __launch_bounds__(256) void gemm_mfma(
    const unsigned short* __restrict__ Abf,   // [16384][512] bf16
    const unsigned short* __restrict__ Wbf,   // [512 or 640][512] bf16
    float* __restrict__ outf,
    unsigned short* __restrict__ outbf,
    const float* __restrict__ bias,
    const float* __restrict__ lw,
    const float* __restrict__ wcol, int wcol_stride,
    const float* __restrict__ bw,
    const float* __restrict__ b_B, const float* __restrict__ b_C,
    float* __restrict__ Bm, float* __restrict__ Cm,
    int mode)
{
    __shared__ __align__(16) short As[2][128 * 32];   // 8 KB per buffer
    __shared__ __align__(16) short Bs[2][128 * 32];   // 8 KB per buffer
    const int tid = threadIdx.x;
    const int wave = tid >> 6, lane = tid & 63;

    // T1 chunked swizzle: valid because nwg (512 or 640) % 8 == 0
    const int nwg  = gridDim.x * gridDim.y;
    const int orig = blockIdx.y * gridDim.x + blockIdx.x;
    const int wsw  = (orig & 7) * (nwg >> 3) + (orig >> 3);
    const int bx   = wsw % gridDim.x;
    const int by   = wsw / gridDim.x;
    const int row0 = by * 128;
    const int col0 = bx * 128;

    const int wr = (wave >> 1) * 64;     // wave's 64-row strip
    const int wc = (wave & 1) * 64;      // wave's 64-col strip

    floatx4 acc[4][4] = {};

    const int srow = lane >> 2;                       // 0..15
    const int sg   = (lane & 3) ^ ((srow >> 1) & 3);  // XOR swizzle
    const int scol = sg * 8;

    // per-wave staging: A-chunks {wave, wave+4} (16 rows each), same for B
    const unsigned short* Ag = Abf + (size_t)(row0 + wave * 16 + srow) * 512 + scol;
    const unsigned short* Wg = Wbf + (size_t)(col0 + wave * 16 + srow) * 512 + scol;
    char* Al = (char*)&As[0][0] + wave * 1024;
    char* Bl = (char*)&Bs[0][0] + wave * 1024;

    #define STAGE(buf, k0)                                              \
        do {                                                            \
            g2lds16(Ag + (k0),            Al + (buf) * 8192);           \
            g2lds16(Ag + 64 * 512 + (k0), Al + (buf) * 8192 + 4096);    \
            g2lds16(Wg + (k0),            Bl + (buf) * 8192);           \
            g2lds16(Wg + 64 * 512 + (k0), Bl + (buf) * 8192 + 4096);    \
        } while (0)

    STAGE(0, 0);
    __syncthreads();

    for (int it = 0; it < 16; ++it) {
        const int cur = it & 1;
        if (it < 15) STAGE(cur ^ 1, (it + 1) * 32);

        short8 af[4], bfr[4];
        #pragma unroll
        for (int i = 0; i < 4; i++) {
            int m = wr + i * 16 + (lane & 15);
            int gm = (lane >> 4) ^ ((m >> 1) & 3);
            af[i] = *(const short8*)&As[cur][m * 32 + gm * 8];
        }
        #pragma unroll
        for (int j = 0; j < 4; j++) {
            int n = wc + j * 16 + (lane & 15);
            int gn = (lane >> 4) ^ ((n >> 1) & 3);
            bfr[j] = *(const short8*)&Bs[cur][n * 32 + gn * 8];
        }
        #pragma unroll
        for (int i = 0; i < 4; i++)
            #pragma unroll
            for (int j = 0; j < 4; j++)
                acc[i][j] = __builtin_amdgcn_mfma_f32_16x16x32_bf16(af[i], bfr[j], acc[i][j], 0, 0, 0);
        __syncthreads();   // drains prefetch vmcnt + guards buffer reuse
    }
    #undef STAGE

    // epilogue: C/D layout col=lane&15, row=(lane>>4)*4+reg
    if (col0 >= 512) {
        // B/C tile: logical cols 512..543 -> Bm/Cm; cols >=544 are zero padding
        #pragma unroll
        for (int i = 0; i < 4; i++) {
            #pragma unroll
            for (int reg = 0; reg < 4; reg++) {
                int r = row0 + wr + i * 16 + (lane >> 4) * 4 + reg;
                #pragma unroll
                for (int j = 0; j < 4; j++) {
                    int c2 = wc + j * 16 + (lane & 15);   // 0..127 within tile
                    float z = acc[i][j][reg];
                    if (c2 < 16)      Bm[(size_t)r * 16 + c2]        = z + b_B[c2];
                    else if (c2 < 32) Cm[(size_t)r * 16 + (c2 - 16)] = z + b_C[c2 - 16];
                }
            }
        }
        return;
    }

    #pragma unroll
    for (int i = 0; i < 4; i++) {
        #pragma unroll
        for (int reg = 0; reg < 4; reg++) {
            int r = row0 + wr + i * 16 + (lane >> 4) * 4 + reg;
            float lwr = lw[r];
            #pragma unroll
            for (int j = 0; j < 4; j++) {
                int c = col0 + wc + j * 16 + (lane & 15);
                float z = acc[i][j][reg] + bias[c];
                if (mode == 0) {
                    float o = z + lwr * wcol[(size_t)c * wcol_stride];
                    outbf[(size_t)r * 512 + c] = f2bf(o);
                } else {
                    // fast softplus: __logf (v_log based) instead of libm log1pf
                    float sp = (z > 15.f) ? z : __logf(1.f + __expf(z));
                    // fast sigmoid: v_rcp instead of full-precision fp32 divide
                    float sg2 = __builtin_amdgcn_rcpf(1.f + __expf(-(lwr * wcol[c] + bw[c])));
                    outf[(size_t)r * 512 + c] = sp * sg2;
                }
            }
        }
    }
}

// fast path valid when As[s] == (s+1)*As[0]
__device__ __forceinline__ bool geo_check(const float* As) {
    bool ok = true;
    #pragma unroll
    for (int s = 1; s < 16; s++) {
        float want = (float)(s + 1) * As[0];
        ok = ok && (fabsf(As[s] - want) <= 1e-4f * (float)(s + 1));
    }
    return ok;
}

// ---------------- shallow scan (nodes 0..510, levels 0..8): walk + LN ----------------
__global__ __launch_bounds__(256) void scan_shallow(
    const unsigned short* __restrict__ x_bf, const float* __restrict__ delta,
    const float* __restrict__ Bm, const float* __restrict__ Cm,
    const float* __restrict__ A_log, const float* __restrict__ Dv,
    const float* __restrict__ gamma, const float* __restrict__ beta,
    float* __restrict__ out)
{
    const int n = blockIdx.x;
    const int t = threadIdx.x;
    const int d0 = t, d1 = t + 256;

    float As0[16], As1[16], acc0[16], acc1[16];
    #pragma unroll
    for (int s = 0; s < 16; s++) {
        As0[s] = -__expf(A_log[d0 * 16 + s]);
        As1[s] = -__expf(A_log[d1 * 16 + s]);
        acc0[s] = 0.f; acc1[s] = 0.f;
    }
    const bool fast = geo_check(As0) && geo_check(As1);

    float cum0 = 0.f, cum1 = 0.f;
    int a = n;
    while (a >= 0) {
        float da0 = delta[(size_t)a * 512 + d0];
        float da1 = delta[(size_t)a * 512 + d1];
        float bx0 = da0 * bf2f(x_bf[(size_t)a * 512 + d0]);
        float bx1 = da1 * bf2f(x_bf[(size_t)a * 512 + d1]);
        if (fast) {
            float r0 = __expf(As0[0] * cum0);
            float r1 = __expf(As1[0] * cum1);
            float pw0 = r0, pw1 = r1;
            #pragma unroll
            for (int s = 0; s < 16; s++) {
                float Bs = Bm[a * 16 + s];
                acc0[s] = fmaf(bx0 * pw0, Bs, acc0[s]);
                acc1[s] = fmaf(bx1 * pw1, Bs, acc1[s]);
                pw0 *= r0; pw1 *= r1;
            }
        } else {
            #pragma unroll
            for (int s = 0; s < 16; s++) {
                float Bs = Bm[a * 16 + s];
                acc0[s] = fmaf(bx0 * __expf(As0[s] * cum0), Bs, acc0[s]);
                acc1[s] = fmaf(bx1 * __expf(As1[s] * cum1), Bs, acc1[s]);
            }
        }
        cum0 += da0; cum1 += da1;
        a = (a - 1) >> 1;
    }

    float xn0 = bf2f(x_bf[(size_t)n * 512 + d0]);
    float xn1 = bf2f(x_bf[(size_t)n * 512 + d1]);
    float y0 = Dv[d0] * xn0, y1 = Dv[d1] * xn1;
    #pragma unroll
    for (int s = 0; s < 16; s++) {
        float Cs = Cm[(size_t)n * 16 + s];
        y0 += Cs * acc0[s];
        y1 += Cs * acc1[s];
    }

    float s1 = y0 + y1;
    float s2 = y0 * y0 + y1 * y1;
    #pragma unroll
    for (int off = 32; off > 0; off >>= 1) {
        s1 += __shfl_xor(s1, off);
        s2 += __shfl_xor(s2, off);
    }
    __shared__ float red[8];
    int wid = t >> 6, lane = t & 63;
    if (lane == 0) { red[wid] = s1; red[wid + 4] = s2; }
    __syncthreads();
    float S1 = red[0] + red[1] + red[2] + red[3];
    float S2 = red[4] + red[5] + red[6] + red[7];
    float mu = S1 * (1.f / 512.f);
    float var = S2 * (1.f / 512.f) - mu * mu;
    float inv = rsqrtf(var + 1e-5f);
    out[(size_t)n * 512 + d0] = (y0 - mu) * inv * gamma[d0] + beta[d0];
    out[(size_t)n * 512 + d1] = (y1 - mu) * inv * gamma[d1] + beta[d1];
}

// ---------------- deep scan (fused ckpt): one block per level-9 subtree ----------------
// Inline ancestor walk (10 steps) builds H at the level-9 root in registers,
// then DFS forward sweep over the 31-node subtree (levels 9..13) + LN.
__global__ __launch_bounds__(512) void scan_deep(
    const unsigned short* __restrict__ x_bf, const float* __restrict__ delta,
    const float* __restrict__ Bm, const float* __restrict__ Cm,
    const float* __restrict__ A_log, const float* __restrict__ Dv,
    const float* __restrict__ gamma, const float* __restrict__ beta,
    float* __restrict__ out)
{
    __shared__ float Y[31][512];
    __shared__ int nid[31];
    const int p = blockIdx.x;
    const int d = threadIdx.x;
    const int a9 = CKPT_BASE + p;

    float As0 = -__expf(A_log[d * 16]);
    bool fast = true;
    #pragma unroll
    for (int s = 1; s < 16; s++) {
        float As = -__expf(A_log[d * 16 + s]);
        fast = fast && (fabsf(As - (float)(s + 1) * As0) <= 1e-4f * (float)(s + 1));
    }

    // ---- inline checkpoint walk: H at node a9 (was ckpt_kernel) ----
    float H9v[16];
    #pragma unroll
    for (int s = 0; s < 16; s++) H9v[s] = 0.f;
    {
        float cum = 0.f;
        int a = a9;
        while (a >= 0) {
            float da = delta[(size_t)a * 512 + d];
            float bx = da * bf2f(x_bf[(size_t)a * 512 + d]);
            if (fast) {
                float r = __expf(As0 * cum);
                float pw = r;
                #pragma unroll
                for (int s = 0; s < 16; s++) {
                    H9v[s] = fmaf(bx * pw, Bm[a * 16 + s], H9v[s]);
                    pw *= r;
                }
            } else {
                #pragma unroll
                for (int s = 0; s < 16; s++) {
                    float As = -__expf(A_log[d * 16 + s]);
                    H9v[s] = fmaf(bx * __expf(As * cum), Bm[a * 16 + s], H9v[s]);
                }
            }
            cum += da;
            a = (a - 1) >> 1;
        }
    }

    {
        float xv = bf2f(x_bf[(size_t)a9 * 512 + d]);
        float y = Dv[d] * xv;
        #pragma unroll
        for (int s = 0; s < 16; s++) y = fmaf(Cm[(size_t)a9 * 16 + s], H9v[s], y);
        Y[0][d] = y;
        if (d == 0) nid[0] = a9;
    }

    auto step = [&](int n, const float* Hp, float* Hc, int slot) {
        float dlt = delta[(size_t)n * 512 + d];
        float xv = bf2f(x_bf[(size_t)n * 512 + d]);
        float bx = dlt * xv;
        const float* Bn = Bm + (size_t)n * 16;
        const float* Cn = Cm + (size_t)n * 16;
        float y = Dv[d] * xv;
        if (fast) {
            float r = __expf(As0 * dlt);
            float pw = r;
            #pragma unroll
            for (int s = 0; s < 16; s++) {
                Hc[s] = fmaf(pw, Hp[s], bx * Bn[s]);
                y = fmaf(Cn[s], Hc[s], y);
                pw *= r;
            }
        } else {
            #pragma unroll
            for (int s = 0; s < 16; s++) {
                float Ab = __expf(dlt * (-__expf(A_log[d * 16 + s])));
                Hc[s] = fmaf(Ab, Hp[s], bx * Bn[s]);
                y = fmaf(Cn[s], Hc[s], y);
            }
        }
        Y[slot][d] = y;
        if (d == 0) nid[slot] = n;
    };

    float H10[16], H11[16], H12[16], H13[16];
    int slot = 1;
    #pragma unroll
    for (int c0 = 0; c0 < 2; c0++) {
        int n10 = 2 * a9 + 1 + c0;
        step(n10, H9v, H10, slot++);
        #pragma unroll
        for (int c1 = 0; c1 < 2; c1++) {
            int n11 = 2 * n10 + 1 + c1;
            step(n11, H10, H11, slot++);
            #pragma unroll
            for (int c2 = 0; c2 < 2; c2++) {
                int n12 = 2 * n11 + 1 + c2;
                step(n12, H11, H12, slot++);
                #pragma unroll
                for (int c3 = 0; c3 < 2; c3++) {
                    int n13 = 2 * n12 + 1 + c3;
                    step(n13, H12, H13, slot++);
                }
            }
        }
    }
    __syncthreads();

    const int w = d >> 6, lane = d & 63;
    for (int i = w; i < 31; i += 8) {
        int n = nid[i];
        float v[8]; float s1 = 0.f, s2 = 0.f;
        #pragma unroll
        for (int k = 0; k < 8; k++) {
            v[k] = Y[i][lane + 64 * k];
            s1 += v[k]; s2 += v[k] * v[k];
        }
        #pragma unroll
        for (int off = 32; off > 0; off >>= 1) {
            s1 += __shfl_xor(s1, off);
            s2 += __shfl_xor(s2, off);
        }
        float mu = s1 * (1.f / 512.f);
        float inv = rsqrtf(s2 * (1.f / 512.f) - mu * mu + 1e-5f);
        #pragma unroll
        for (int k = 0; k < 8; k++) {
            int ch = lane + 64 * k;
            out[(size_t)n * 512 + ch] = (v[k] - mu) * inv * gamma[ch] + beta[ch];
        }
    }
}

extern "C" void kernel_launch(void* const* d_in, const int* in_sizes, int n_in,
                              void* d_out, int out_size, void* d_ws, size_t ws_size,
                              hipStream_t stream) {
    const float* s_in   = (const float*)d_in[0];
    const float* w      = (const float*)d_in[1];
    const float* W_in    = (const float*)d_in[4];
    const float* b_in    = (const float*)d_in[5];
    const float* W_delta = (const float*)d_in[6];
    const float* b_delta = (const float*)d_in[7];
    const float* W_w     = (const float*)d_in[8];
    const float* b_w     = (const float*)d_in[9];
    const float* A_log   = (const float*)d_in[10];
    const float* Dv      = (const float*)d_in[11];
    const float* W_B     = (const float*)d_in[12];
    const float* b_B     = (const float*)d_in[13];
    const float* W_C     = (const float*)d_in[14];
    const float* b_C     = (const float*)d_in[15];
    const float* gamma   = (const float*)d_in[16];
    const float* beta    = (const float*)d_in[17];
    float* out = (float*)d_out;

    const int Nn = in_sizes[1];           // 16383

    float* ws    = (float*)d_ws;
    float* lw    = ws;                                      // 16384
    float* delta = lw + MPAD;                               // 16384*512 fp32
    float* Bm    = delta + (size_t)MPAD * 512;              // 16384*16
    float* Cm    = Bm + (size_t)MPAD * 16;                  // 16384*16
    unsigned short* s_bf  = (unsigned short*)(Cm + (size_t)MPAD * 16);  // 16384*512
    unsigned short* x_bf  = s_bf + (size_t)MPAD * 512;      // 16384*512
    unsigned short* Win_bf = x_bf + (size_t)MPAD * 512;     // 512*512
    unsigned short* Wd_bf  = Win_bf + 512 * 512;            // 640*512 (delta + B + C + pad)

    prep_kernel<<<MPAD + 1024 + 128, 256, 0, stream>>>(s_in, w, W_in, W_delta, W_B, W_C,
                                                       s_bf, lw, Win_bf, Wd_bf, Nn);

    dim3 g1(4, 128);   // 128-col x 128-row tiles -> 512 blocks
    gemm_mfma<<<g1, 256, 0, stream>>>(s_bf, Win_bf, nullptr, x_bf,
                                      b_in, lw, W_in + 512, 513, nullptr,
                                      nullptr, nullptr, nullptr, nullptr, 0);
    dim3 g2(5, 128);   // 5th col tile = B/C columns
    gemm_mfma<<<g2, 256, 0, stream>>>(x_bf, Wd_bf, delta, nullptr,
                                      b_delta, lw, W_w, 1, b_w,
                                      b_B, b_C, Bm, Cm, 1);

    scan_shallow<<<CKPT_BASE, 256, 0, stream>>>(x_bf, delta, Bm, Cm, A_log, Dv,
                                                gamma, beta, out);

    scan_deep<<<N_CKPT, 512, 0, stream>>>(x_bf, delta, Bm, Cm, A_log, Dv,
                                          gamma, beta, out);
}

// Round 4
// 222.226 us; speedup vs baseline: 1.2002x; 1.0153x over previous
//
#include <hip/hip_runtime.h>
#include <hip/hip_bf16.h>
#include <math.h>

#define D_SSM 512
#define D_STATE 16
#define CKPT_BASE 511     // first index of level 9
#define N_CKPT 512        // nodes at level 9
#define MPAD 16384

typedef __attribute__((ext_vector_type(8))) short short8;
typedef __attribute__((ext_vector_type(4))) float floatx4;

__device__ __forceinline__ unsigned short f2bf(float f) {
    unsigned int u = __float_as_uint(f);
    unsigned int r = (u + 0x7fffu + ((u >> 16) & 1u)) >> 16;
    return (unsigned short)r;
}
__device__ __forceinline__ float bf2f(unsigned short u) {
    return __uint_as_float(((unsigned int)u) << 16);
}
__device__ __forceinline__ void g2lds16(const void* g, void* l) {
    __builtin_amdgcn_global_load_lds(
        (const __attribute__((address_space(1))) void*)g,
        (__attribute__((address_space(3))) void*)l, 16, 0, 0);
}

// r^(s+1) for s=0..15, dependency depth 4 instead of 16
__device__ __forceinline__ void pw_powers(float r, float* p) {
    float r2 = r * r, r4 = r2 * r2, r8 = r4 * r4;
    p[0] = r;          p[1] = r2;         p[2] = r2 * r;     p[3] = r4;
    p[4] = r4 * r;     p[5] = r4 * r2;    p[6] = r4 * p[2];  p[7] = r8;
    p[8] = r8 * r;     p[9] = r8 * r2;    p[10] = r8 * p[2]; p[11] = r8 * r4;
    p[12] = r8 * p[4]; p[13] = r8 * p[5]; p[14] = r8 * p[6]; p[15] = r8 * r8;
}

// ---------------- prep: cast s/W_in/W_delta to bf16; W2 = [W_delta; W_B; W_C; 0] (640 rows) ----------------
__global__ __launch_bounds__(256) void prep_kernel(
    const float* __restrict__ s, const float* __restrict__ w,
    const float* __restrict__ W_in, const float* __restrict__ W_delta,
    const float* __restrict__ W_B, const float* __restrict__ W_C,
    unsigned short* __restrict__ s_bf, float* __restrict__ lw,
    unsigned short* __restrict__ Win_bf, unsigned short* __restrict__ Wd_bf,
    int Nn)
{
    const int b = blockIdx.x, t = threadIdx.x;
    if (b < MPAD) {
        unsigned int pack = 0;
        if (b < Nn) {
            float2 sv = *(const float2*)(s + (size_t)b * 512 + t * 2);
            pack = (unsigned int)f2bf(sv.x) | ((unsigned int)f2bf(sv.y) << 16);
        }
        *(unsigned int*)(s_bf + (size_t)b * 512 + t * 2) = pack;
        if (t == 0) lw[b] = (b < Nn) ? logf(w[b] + 1e-6f) : 0.f;
    } else if (b < MPAD + 512) {
        int c = b - MPAD;
        float a0 = W_in[(size_t)c * 513 + t * 2];
        float a1 = W_in[(size_t)c * 513 + t * 2 + 1];
        *(unsigned int*)(Win_bf + (size_t)c * 512 + t * 2) =
            (unsigned int)f2bf(a0) | ((unsigned int)f2bf(a1) << 16);
    } else if (b < MPAD + 1024) {
        int c = b - MPAD - 512;
        float2 wv = *(const float2*)(W_delta + (size_t)c * 512 + t * 2);
        *(unsigned int*)(Wd_bf + (size_t)c * 512 + t * 2) =
            (unsigned int)f2bf(wv.x) | ((unsigned int)f2bf(wv.y) << 16);
    } else {
        // rows 512..639 of W2: 0..15 = W_B, 16..31 = W_C, rest zero padding
        int c = b - MPAD - 1024;   // 0..127
        float2 wv; wv.x = 0.f; wv.y = 0.f;
        if (c < 16)      wv = *(const float2*)(W_B + (size_t)c * 512 + t * 2);
        else if (c < 32) wv = *(const float2*)(W_C + (size_t)(c - 16) * 512 + t * 2);
        *(unsigned int*)(Wd_bf + (size_t)(512 + c) * 512 + t * 2) =
            (unsigned int)f2bf(wv.x) | ((unsigned int)f2bf(wv.y) << 16);
    }
}

// ---------------- bf16 MFMA GEMM, 128x128 tile (m97 structure), double-buffered LDS ----------------
__global__ __launch_bounds__(256) void gemm_mfma(
    const unsigned short* __restrict__ Abf,   // [16384][512] bf16
    const unsigned short* __restrict__ Wbf,   // [512 or 640][512] bf16
    float* __restrict__ outf,
    unsigned short* __restrict__ outbf,
    const float* __restrict__ bias,
    const float* __restrict__ lw,
    const float* __restrict__ wcol, int wcol_stride,
    const float* __restrict__ bw,
    const float* __restrict__ b_B, const float* __restrict__ b_C,
    float* __restrict__ Bm, float* __restrict__ Cm,
    int mode)
{
    __shared__ __align__(16) short As[2][128 * 32];   // 8 KB per buffer
    __shared__ __align__(16) short Bs[2][128 * 32];   // 8 KB per buffer
    const int tid = threadIdx.x;
    const int wave = tid >> 6, lane = tid & 63;

    // T1 chunked swizzle: valid because nwg (512 or 640) % 8 == 0
    const int nwg  = gridDim.x * gridDim.y;
    const int orig = blockIdx.y * gridDim.x + blockIdx.x;
    const int wsw  = (orig & 7) * (nwg >> 3) + (orig >> 3);
    const int bx   = wsw % gridDim.x;
    const int by   = wsw / gridDim.x;
    const int row0 = by * 128;
    const int col0 = bx * 128;

    const int wr = (wave >> 1) * 64;     // wave's 64-row strip
    const int wc = (wave & 1) * 64;      // wave's 64-col strip

    floatx4 acc[4][4] = {};

    const int srow = lane >> 2;                       // 0..15
    const int sg   = (lane & 3) ^ ((srow >> 1) & 3);  // XOR swizzle
    const int scol = sg * 8;

    const unsigned short* Ag = Abf + (size_t)(row0 + wave * 16 + srow) * 512 + scol;
    const unsigned short* Wg = Wbf + (size_t)(col0 + wave * 16 + srow) * 512 + scol;
    char* Al = (char*)&As[0][0] + wave * 1024;
    char* Bl = (char*)&Bs[0][0] + wave * 1024;

    #define STAGE(buf, k0)                                              \
        do {                                                            \
            g2lds16(Ag + (k0),            Al + (buf) * 8192);           \
            g2lds16(Ag + 64 * 512 + (k0), Al + (buf) * 8192 + 4096);    \
            g2lds16(Wg + (k0),            Bl + (buf) * 8192);           \
            g2lds16(Wg + 64 * 512 + (k0), Bl + (buf) * 8192 + 4096);    \
        } while (0)

    STAGE(0, 0);
    __syncthreads();

    for (int it = 0; it < 16; ++it) {
        const int cur = it & 1;
        if (it < 15) STAGE(cur ^ 1, (it + 1) * 32);

        short8 af[4], bfr[4];
        #pragma unroll
        for (int i = 0; i < 4; i++) {
            int m = wr + i * 16 + (lane & 15);
            int gm = (lane >> 4) ^ ((m >> 1) & 3);
            af[i] = *(const short8*)&As[cur][m * 32 + gm * 8];
        }
        #pragma unroll
        for (int j = 0; j < 4; j++) {
            int n = wc + j * 16 + (lane & 15);
            int gn = (lane >> 4) ^ ((n >> 1) & 3);
            bfr[j] = *(const short8*)&Bs[cur][n * 32 + gn * 8];
        }
        #pragma unroll
        for (int i = 0; i < 4; i++)
            #pragma unroll
            for (int j = 0; j < 4; j++)
                acc[i][j] = __builtin_amdgcn_mfma_f32_16x16x32_bf16(af[i], bfr[j], acc[i][j], 0, 0, 0);
        __syncthreads();   // drains prefetch vmcnt + guards buffer reuse
    }
    #undef STAGE

    // epilogue: C/D layout col=lane&15, row=(lane>>4)*4+reg
    if (col0 >= 512) {
        #pragma unroll
        for (int i = 0; i < 4; i++) {
            #pragma unroll
            for (int reg = 0; reg < 4; reg++) {
                int r = row0 + wr + i * 16 + (lane >> 4) * 4 + reg;
                #pragma unroll
                for (int j = 0; j < 4; j++) {
                    int c2 = wc + j * 16 + (lane & 15);   // 0..127 within tile
                    float z = acc[i][j][reg];
                    if (c2 < 16)      Bm[(size_t)r * 16 + c2]        = z + b_B[c2];
                    else if (c2 < 32) Cm[(size_t)r * 16 + (c2 - 16)] = z + b_C[c2 - 16];
                }
            }
        }
        return;
    }

    #pragma unroll
    for (int i = 0; i < 4; i++) {
        #pragma unroll
        for (int reg = 0; reg < 4; reg++) {
            int r = row0 + wr + i * 16 + (lane >> 4) * 4 + reg;
            float lwr = lw[r];
            #pragma unroll
            for (int j = 0; j < 4; j++) {
                int c = col0 + wc + j * 16 + (lane & 15);
                float z = acc[i][j][reg] + bias[c];
                if (mode == 0) {
                    float o = z + lwr * wcol[(size_t)c * wcol_stride];
                    outbf[(size_t)r * 512 + c] = f2bf(o);
                } else {
                    float sp = (z > 15.f) ? z : __logf(1.f + __expf(z));
                    float sg2 = __builtin_amdgcn_rcpf(1.f + __expf(-(lwr * wcol[c] + bw[c])));
                    outf[(size_t)r * 512 + c] = sp * sg2;
                }
            }
        }
    }
}

// ---------------- shallow scan (nodes 0..510, levels 0..8): 512 threads, 1 channel each ----------------
__global__ __launch_bounds__(512) void scan_shallow(
    const unsigned short* __restrict__ x_bf, const float* __restrict__ delta,
    const float* __restrict__ Bm, const float* __restrict__ Cm,
    const float* __restrict__ A_log, const float* __restrict__ Dv,
    const float* __restrict__ gamma, const float* __restrict__ beta,
    float* __restrict__ out)
{
    __shared__ __align__(16) float Banc[9][16];   // B of ancestors (k=0 is n itself)
    __shared__ __align__(16) float Cn[16];
    __shared__ float red[16];
    const int n = blockIdx.x;
    const int d = threadIdx.x;

    // preload block-uniform B/C into LDS (parallel)
    if (d < 144) {
        int k = d >> 4, s = d & 15;
        int a = n;
        for (int q = 0; q < 9; q++) if (q < k) a = (a < 0) ? -1 : ((a - 1) >> 1);
        Banc[k][s] = (a >= 0) ? Bm[(size_t)a * 16 + s] : 0.f;
    }
    if (d >= 240 && d < 256) Cn[d - 240] = Cm[(size_t)n * 16 + (d - 240)];
    __syncthreads();

    float As0 = -__expf(A_log[d * 16]);
    bool fast = true;
    #pragma unroll
    for (int s = 1; s < 16; s++) {
        float As = -__expf(A_log[d * 16 + s]);
        fast = fast && (fabsf(As - (float)(s + 1) * As0) <= 1e-4f * (float)(s + 1));
    }

    float acc[16];
    #pragma unroll
    for (int s = 0; s < 16; s++) acc[s] = 0.f;

    float cum = 0.f;
    int a = n;
    #pragma unroll
    for (int k = 0; k < 9; k++) {
        if (a >= 0) {
            float da = delta[(size_t)a * 512 + d];
            float bx = da * bf2f(x_bf[(size_t)a * 512 + d]);
            if (fast) {
                float r = __expf(As0 * cum);
                float pw[16]; pw_powers(r, pw);
                const floatx4* B4 = (const floatx4*)&Banc[k][0];
                #pragma unroll
                for (int q = 0; q < 4; q++) {
                    floatx4 b = B4[q];
                    #pragma unroll
                    for (int u = 0; u < 4; u++) {
                        int s = q * 4 + u;
                        acc[s] = fmaf(bx * pw[s], b[u], acc[s]);
                    }
                }
            } else {
                #pragma unroll
                for (int s = 0; s < 16; s++) {
                    float As = -__expf(A_log[d * 16 + s]);
                    acc[s] = fmaf(bx * __expf(As * cum), Banc[k][s], acc[s]);
                }
            }
            cum += da;
            a = (a - 1) >> 1;
        }
    }

    float xv = bf2f(x_bf[(size_t)n * 512 + d]);
    float y0 = 0.f, y1 = 0.f;
    const floatx4* C4 = (const floatx4*)&Cn[0];
    #pragma unroll
    for (int q = 0; q < 4; q++) {
        floatx4 c = C4[q];
        #pragma unroll
        for (int u = 0; u < 4; u++) {
            int s = q * 4 + u;
            if (s & 1) y1 = fmaf(c[u], acc[s], y1);
            else       y0 = fmaf(c[u], acc[s], y0);
        }
    }
    float y = fmaf(Dv[d], xv, y0 + y1);

    float s1 = y, s2 = y * y;
    #pragma unroll
    for (int off = 32; off > 0; off >>= 1) {
        s1 += __shfl_xor(s1, off);
        s2 += __shfl_xor(s2, off);
    }
    int wid = d >> 6, lane = d & 63;
    if (lane == 0) { red[wid] = s1; red[wid + 8] = s2; }
    __syncthreads();
    float S1 = 0.f, S2 = 0.f;
    #pragma unroll
    for (int k = 0; k < 8; k++) { S1 += red[k]; S2 += red[k + 8]; }
    float mu = S1 * (1.f / 512.f);
    float var = S2 * (1.f / 512.f) - mu * mu;
    float inv = rsqrtf(var + 1e-5f);
    out[(size_t)n * 512 + d] = (y - mu) * inv * gamma[d] + beta[d];
}

// ---------------- deep scan (fused ckpt): one block per level-9 subtree ----------------
// LDS-preloaded B/C (block-uniform), log-depth power ladder, branch-wise LN flush.
__global__ __launch_bounds__(512) void scan_deep(
    const unsigned short* __restrict__ x_bf, const float* __restrict__ delta,
    const float* __restrict__ Bm, const float* __restrict__ Cm,
    const float* __restrict__ A_log, const float* __restrict__ Dv,
    const float* __restrict__ gamma, const float* __restrict__ beta,
    float* __restrict__ out)
{
    __shared__ float Y[16][512];                   // 32 KB: one c0-branch of outputs
    __shared__ __align__(16) float BCs[31][32];    // subtree B(0:16)/C(16:32), BFS order
    __shared__ __align__(16) float Banc[10][16];   // ancestor B (k=0 is a9)
    __shared__ int nid[16];
    const int p = blockIdx.x;
    const int d = threadIdx.x;
    const int a9 = CKPT_BASE + p;

    // preload block-uniform B/C into LDS (parallel over all threads)
    for (int idx = d; idx < 31 * 32; idx += 512) {
        int i = idx >> 5, c = idx & 31;
        int v = i + 1;
        int j = 31 - __builtin_clz((unsigned)v);
        int node = ((a9 + 1) << j) - 1 + (v - (1 << j));
        BCs[i][c] = (c < 16) ? Bm[(size_t)node * 16 + c] : Cm[(size_t)node * 16 + (c - 16)];
    }
    if (d < 160) {
        int k = d >> 4, s = d & 15;
        int a = a9;
        for (int q = 0; q < k; q++) a = (a - 1) >> 1;
        Banc[k][s] = Bm[(size_t)a * 16 + s];
    }
    __syncthreads();

    float As0 = -__expf(A_log[d * 16]);
    bool fast = true;
    #pragma unroll
    for (int s = 1; s < 16; s++) {
        float As = -__expf(A_log[d * 16 + s]);
        fast = fast && (fabsf(As - (float)(s + 1) * As0) <= 1e-4f * (float)(s + 1));
    }
    const float dvd = Dv[d];

    // ---- inline checkpoint walk: H at node a9 (10 fixed, fully-unrolled levels) ----
    float H9v[16];
    #pragma unroll
    for (int s = 0; s < 16; s++) H9v[s] = 0.f;
    {
        float cum = 0.f;
        int a = a9;
        #pragma unroll
        for (int k = 0; k < 10; k++) {
            float da = delta[(size_t)a * 512 + d];
            float bx = da * bf2f(x_bf[(size_t)a * 512 + d]);
            if (fast) {
                float r = __expf(As0 * cum);
                float pw[16]; pw_powers(r, pw);
                const floatx4* B4 = (const floatx4*)&Banc[k][0];
                #pragma unroll
                for (int q = 0; q < 4; q++) {
                    floatx4 b = B4[q];
                    #pragma unroll
                    for (int u = 0; u < 4; u++) {
                        int s = q * 4 + u;
                        H9v[s] = fmaf(bx * pw[s], b[u], H9v[s]);
                    }
                }
            } else {
                #pragma unroll
                for (int s = 0; s < 16; s++) {
                    float As = -__expf(A_log[d * 16 + s]);
                    H9v[s] = fmaf(bx * __expf(As * cum), Banc[k][s], H9v[s]);
                }
            }
            cum += da;
            a = (a - 1) >> 1;
        }
    }

    auto step = [&](int n, int bfs, const float* Hp, float* Hc, int slot) {
        float dlt = delta[(size_t)n * 512 + d];
        float xv = bf2f(x_bf[(size_t)n * 512 + d]);
        float bx = dlt * xv;
        const floatx4* B4 = (const floatx4*)&BCs[bfs][0];
        const floatx4* C4 = (const floatx4*)&BCs[bfs][16];
        float y0 = 0.f, y1 = 0.f;
        if (fast) {
            float r = __expf(As0 * dlt);
            float pw[16]; pw_powers(r, pw);
            #pragma unroll
            for (int q = 0; q < 4; q++) {
                floatx4 b = B4[q], c = C4[q];
                #pragma unroll
                for (int u = 0; u < 4; u++) {
                    int s = q * 4 + u;
                    Hc[s] = fmaf(pw[s], Hp[s], bx * b[u]);
                    if (s & 1) y1 = fmaf(c[u], Hc[s], y1);
                    else       y0 = fmaf(c[u], Hc[s], y0);
                }
            }
        } else {
            #pragma unroll
            for (int s = 0; s < 16; s++) {
                float Ab = __expf(dlt * (-__expf(A_log[d * 16 + s])));
                Hc[s] = fmaf(Ab, Hp[s], bx * BCs[bfs][s]);
                float cc = BCs[bfs][16 + s];
                if (s & 1) y1 = fmaf(cc, Hc[s], y1);
                else       y0 = fmaf(cc, Hc[s], y0);
            }
        }
        Y[slot][d] = fmaf(dvd, xv, y0 + y1);
        if (d == 0) nid[slot] = n;
    };

    auto flush = [&](int cnt) {
        const int w = d >> 6, lane = d & 63;
        for (int i = w; i < cnt; i += 8) {
            int n = nid[i];
            float v[8]; float s1 = 0.f, s2 = 0.f;
            #pragma unroll
            for (int k = 0; k < 8; k++) {
                v[k] = Y[i][lane + 64 * k];
                s1 += v[k]; s2 += v[k] * v[k];
            }
            #pragma unroll
            for (int off = 32; off > 0; off >>= 1) {
                s1 += __shfl_xor(s1, off);
                s2 += __shfl_xor(s2, off);
            }
            float mu = s1 * (1.f / 512.f);
            float inv = rsqrtf(s2 * (1.f / 512.f) - mu * mu + 1e-5f);
            #pragma unroll
            for (int k = 0; k < 8; k++) {
                int ch = lane + 64 * k;
                out[(size_t)n * 512 + ch] = (v[k] - mu) * inv * gamma[ch] + beta[ch];
            }
        }
    };

    float H10[16], H11[16], H12[16], H13[16];
    #pragma unroll
    for (int c0 = 0; c0 < 2; c0++) {
        int slot = 0;
        if (c0 == 0) {
            // root row (level-9 node itself)
            float xv = bf2f(x_bf[(size_t)a9 * 512 + d]);
            const floatx4* C4 = (const floatx4*)&BCs[0][16];
            float y0 = 0.f, y1 = 0.f;
            #pragma unroll
            for (int q = 0; q < 4; q++) {
                floatx4 c = C4[q];
                #pragma unroll
                for (int u = 0; u < 4; u++) {
                    int s = q * 4 + u;
                    if (s & 1) y1 = fmaf(c[u], H9v[s], y1);
                    else       y0 = fmaf(c[u], H9v[s], y0);
                }
            }
            Y[0][d] = fmaf(dvd, xv, y0 + y1);
            if (d == 0) nid[0] = a9;
            slot = 1;
        }
        int n10 = 2 * a9 + 1 + c0;
        step(n10, 1 + c0, H9v, H10, slot++);
        #pragma unroll
        for (int c1 = 0; c1 < 2; c1++) {
            int n11 = 2 * n10 + 1 + c1;
            step(n11, 3 + 2 * c0 + c1, H10, H11, slot++);
            #pragma unroll
            for (int c2 = 0; c2 < 2; c2++) {
                int n12 = 2 * n11 + 1 + c2;
                step(n12, 7 + 4 * c0 + 2 * c1 + c2, H11, H12, slot++);
                #pragma unroll
                for (int c3 = 0; c3 < 2; c3++) {
                    int n13 = 2 * n12 + 1 + c3;
                    step(n13, 15 + 8 * c0 + 4 * c1 + 2 * c2 + c3, H12, H13, slot++);
                }
            }
        }
        __syncthreads();           // Y/nid complete for this branch
        flush(c0 == 0 ? 16 : 15);
        __syncthreads();           // Y reads done before next branch overwrites
    }
}

extern "C" void kernel_launch(void* const* d_in, const int* in_sizes, int n_in,
                              void* d_out, int out_size, void* d_ws, size_t ws_size,
                              hipStream_t stream) {
    const float* s_in   = (const float*)d_in[0];
    const float* w      = (const float*)d_in[1];
    const float* W_in    = (const float*)d_in[4];
    const float* b_in    = (const float*)d_in[5];
    const float* W_delta = (const float*)d_in[6];
    const float* b_delta = (const float*)d_in[7];
    const float* W_w     = (const float*)d_in[8];
    const float* b_w     = (const float*)d_in[9];
    const float* A_log   = (const float*)d_in[10];
    const float* Dv      = (const float*)d_in[11];
    const float* W_B     = (const float*)d_in[12];
    const float* b_B     = (const float*)d_in[13];
    const float* W_C     = (const float*)d_in[14];
    const float* b_C     = (const float*)d_in[15];
    const float* gamma   = (const float*)d_in[16];
    const float* beta    = (const float*)d_in[17];
    float* out = (float*)d_out;

    const int Nn = in_sizes[1];           // 16383

    float* ws    = (float*)d_ws;
    float* lw    = ws;                                      // 16384
    float* delta = lw + MPAD;                               // 16384*512 fp32
    float* Bm    = delta + (size_t)MPAD * 512;              // 16384*16
    float* Cm    = Bm + (size_t)MPAD * 16;                  // 16384*16
    unsigned short* s_bf  = (unsigned short*)(Cm + (size_t)MPAD * 16);  // 16384*512
    unsigned short* x_bf  = s_bf + (size_t)MPAD * 512;      // 16384*512
    unsigned short* Win_bf = x_bf + (size_t)MPAD * 512;     // 512*512
    unsigned short* Wd_bf  = Win_bf + 512 * 512;            // 640*512 (delta + B + C + pad)

    prep_kernel<<<MPAD + 1024 + 128, 256, 0, stream>>>(s_in, w, W_in, W_delta, W_B, W_C,
                                                       s_bf, lw, Win_bf, Wd_bf, Nn);

    dim3 g1(4, 128);   // 128-col x 128-row tiles -> 512 blocks
    gemm_mfma<<<g1, 256, 0, stream>>>(s_bf, Win_bf, nullptr, x_bf,
                                      b_in, lw, W_in + 512, 513, nullptr,
                                      nullptr, nullptr, nullptr, nullptr, 0);
    dim3 g2(5, 128);   // 5th col tile = B/C columns
    gemm_mfma<<<g2, 256, 0, stream>>>(x_bf, Wd_bf, delta, nullptr,
                                      b_delta, lw, W_w, 1, b_w,
                                      b_B, b_C, Bm, Cm, 1);

    scan_shallow<<<CKPT_BASE, 512, 0, stream>>>(x_bf, delta, Bm, Cm, A_log, Dv,
                                                gamma, beta, out);

    scan_deep<<<N_CKPT, 512, 0, stream>>>(x_bf, delta, Bm, Cm, A_log, Dv,
                                          gamma, beta, out);
}